// Round 8
// baseline (262.575 us; speedup 1.0000x reference)
//
#include <hip/hip_runtime.h>
#include <math.h>

// excess[b,m] = K·T + SIGMA*e*(T^4 - Tenv^4) - (H+F);  out = mean(|excess|)
// K = 5-band stencil on a 13x13 grid; GLx = -K[1][2]; GR = e_diag[1];
// interface nodes {0,12,156,168} are identity rows with e=0.
//
// v12: wave-private LDS double-buffer + counted vmcnt (T3/T4, barrier-free).
// v10/v11's register pipelines were flattened by regalloc (VGPR 52/56 prove
// it); v9's LDS pipeline was killed by __syncthreads' vmcnt(0) drain. Here
// each WAVE stages its own tile slice (no inter-wave sharing -> no barrier):
//   issue 8 global_load_lds for tile t+1  ->  s_waitcnt vmcnt(8)  (waits only
//   tile t's loads, prefetch stays in flight)  ->  compute tile t from LDS.
// Compute touches ONLY LDS+VALU: T halo (+-16) and a 64-entry Tenv slice are
// staged too, so no global load ever forces a drain. Halo entries clamped at
// the array ends are exactly the geometry-masked (m<13 / m>=156) values.
// Per-elem math = v7's verified mask-table core (absmax 0.0 x3).

#define SIGMA_F 5.67e-8f

constexpr int BLOCK = 256;
constexpr int TILE  = 512;              // elements per wave-tile
// wave buffer layout (floats): T[544] (+-16 halo) | H[512] | F[512] | Env[64]
constexpr int HOFF  = 544;
constexpr int FOFF  = 1056;
constexpr int EOFF  = 1568;
constexpr int SLICE = 1632;             // floats per buffer
constexpr int WSTR  = 2 * SLICE;        // two buffers per wave

typedef float f4b __attribute__((ext_vector_type(4), aligned(16)));

static __device__ __forceinline__ void gl16(const float* g, float* l) {
    __builtin_amdgcn_global_load_lds(
        (const __attribute__((address_space(1))) void*)g,
        (__attribute__((address_space(3))) void*)l, 16, 0, 0);
}
static __device__ __forceinline__ void gl4(const float* g, float* l) {
    __builtin_amdgcn_global_load_lds(
        (const __attribute__((address_space(1))) void*)g,
        (__attribute__((address_space(3))) void*)l, 4, 0, 0);
}

__global__ __launch_bounds__(256) void fused_residual_v12(
    const float* __restrict__ T,      // [B*169]
    const float* __restrict__ H,
    const float* __restrict__ F,
    const float* __restrict__ Tenv,   // [B]
    const float* __restrict__ K,      // [169*169]
    const float* __restrict__ Ediag,  // [169]
    float* __restrict__ partials,
    int total)
{
    __shared__ float    S[4 * WSTR];  // 4 waves x 2 buffers x 1632 floats
    __shared__ unsigned sTab[184];
    __shared__ float    sred[4];

    const int tid  = (int)threadIdx.x;
    const int lane = tid & 63;
    const int wid  = tid >> 6;

    const float GLx = -K[1 * 169 + 2];     // interior coupling (dx==dy)
    const float GRs = SIGMA_F * Ediag[1];  // sigma * GR

    // per-m neighbor-mask table; padded so m0+j needs no mod
    if (tid < 184) {
        int m = (tid < 169) ? tid : tid - 169;
        int ii = m % 13;
        unsigned cW = (ii > 0)  ? 1u : 0u;
        unsigned cE = (ii < 12) ? 1u : 0u;
        unsigned cN = (m < 156) ? 1u : 0u;
        unsigned cS = (m >= 13) ? 1u : 0u;
        sTab[tid] = cW | (cE << 8) | (cN << 16) | (cS << 24);
    }

    float acc = 0.0f;
    const int ntiles = total / TILE;

    // remainder elements (total % 512; zero at the bench size): block 0, scalar
    if (blockIdx.x == 0) {
        for (int e = ntiles * TILE + tid; e < total; e += BLOCK) {
            unsigned bb = (unsigned)e / 169u;
            int m = e - (int)bb * 169;
            int ii = m % 13;
            bool cE = (ii < 12), cW = (ii > 0), cN = (m < 156), cS = (m >= 13);
            bool ifc = (m == 0) | (m == 12) | (m == 156) | (m == 168);
            float t  = T[e];
            float s  = (cE ? T[e + 1] : 0.0f) + (cW ? T[e - 1] : 0.0f)
                     + (cN ? T[e + 13] : 0.0f) + (cS ? T[e - 13] : 0.0f);
            float nn = (float)((int)cE + (int)cW + (int)cN + (int)cS);
            float tv = Tenv[bb];
            float tv4 = (tv * tv) * (tv * tv);
            float t2 = t * t, t4 = t2 * t2;
            float qq = H[e] + F[e];
            acc += fabsf(ifc ? (t - qq)
                             : (GLx * (nn * t - s) + GRs * (t4 - tv4) - qq));
        }
    }
    __syncthreads();   // sTab visible to all waves (single barrier in kernel)

    const int nw    = (int)gridDim.x * 4;     // total waves
    const int tile0 = (int)blockIdx.x * 4 + wid;
    const int wbase = wid * WSTR;
    const int Bm1   = total / 169 - 1;
    const int smax  = total - 4;

    auto STAGE = [&](int buf, int t) {
        const int tb = t * TILE;
        float* sl = &S[wbase + buf * SLICE];
        const int l4 = 4 * lane;
        int s0 = tb - 16 + l4;  s0 = s0 < 0 ? 0 : s0;        // front clamp
        int s2 = tb + 272 + l4; s2 = s2 > smax ? smax : s2;  // back clamp
        gl16(T + s0,            sl + l4);           // Tbuf[  0..256)
        gl16(T + tb + 240 + l4, sl + 256 + l4);     // Tbuf[256..512)
        gl16(T + s2,            sl + 288 + l4);     // Tbuf[288..544) (overlap ok)
        gl16(H + tb + l4,       sl + HOFF + l4);
        gl16(H + tb + 256 + l4, sl + HOFF + 256 + l4);
        gl16(F + tb + l4,       sl + FOFF + l4);
        gl16(F + tb + 256 + l4, sl + FOFF + 256 + l4);
        int bw = (int)((unsigned)tb / 169u) + lane;
        bw = bw > Bm1 ? Bm1 : bw;
        gl4(Tenv + bw, sl + EOFF + lane);
    };

    int buf = 0;
    if (tile0 < ntiles) STAGE(0, tile0);

    for (int t = tile0; t < ntiles; t += nw) {
        const int tn = t + nw;
        if (tn < ntiles) {
            STAGE(buf ^ 1, tn);                     // prefetch next tile
            asm volatile("s_waitcnt vmcnt(8)" ::: "memory");  // tile t ready
        } else {
            asm volatile("s_waitcnt vmcnt(0)" ::: "memory");
        }
        __builtin_amdgcn_sched_barrier(0);

        // ---- compute tile t: LDS + VALU only ----
        const int tb = t * TILE;
        const float* sl = &S[wbase + buf * SLICE];
        const int lb = 16 + lane * 8;

        f4b a0 = *(const f4b*)&sl[lb];
        f4b a1 = *(const f4b*)&sl[lb + 4];
        float sv[8], nv[8];
        #pragma unroll
        for (int j = 0; j < 8; ++j) sv[j] = sl[lb - 13 + j];
        #pragma unroll
        for (int j = 0; j < 8; ++j) nv[j] = sl[lb + 13 + j];
        const float tw0 = sl[lb - 1];
        const float te7 = sl[lb + 8];
        f4b h0 = *(const f4b*)&sl[HOFF + lane * 8];
        f4b h1 = *(const f4b*)&sl[HOFF + lane * 8 + 4];
        f4b f0 = *(const f4b*)&sl[FOFF + lane * 8];
        f4b f1 = *(const f4b*)&sl[FOFF + lane * 8 + 4];

        const int e0 = tb + lane * 8;
        const unsigned b0 = (unsigned)e0 / 169u;             // magic-mul
        const int m0 = e0 - (int)(b0 * 169u);
        const int b0w = (int)((unsigned)tb / 169u);
        const int relb = (int)b0 - b0w;                      // 0..3
        const float tvA = sl[EOFF + relb];
        const float tvB = sl[EOFF + relb + 1];
        const float tv4A = (tvA * tvA) * (tvA * tvA);
        const float tv4B = (tvB * tvB) * (tvB * tvB);

        const float tCv[8] = {a0.x, a0.y, a0.z, a0.w, a1.x, a1.y, a1.z, a1.w};
        const float tWv[8] = {tw0, a0.x, a0.y, a0.z, a0.w, a1.x, a1.y, a1.z};
        const float tEv[8] = {a0.y, a0.z, a0.w, a1.x, a1.y, a1.z, a1.w, te7};
        const float qv[8]  = {h0.x + f0.x, h0.y + f0.y, h0.z + f0.z, h0.w + f0.w,
                              h1.x + f1.x, h1.y + f1.y, h1.z + f1.z, h1.w + f1.w};

        #pragma unroll
        for (int j = 0; j < 8; ++j) {
            const unsigned w = sTab[m0 + j];            // padded table: no mod
            const float mW = (float)(w & 0xffu);        // v_cvt_f32_ubyte0..3
            const float mE = (float)((w >> 8) & 0xffu);
            const float mN = (float)((w >> 16) & 0xffu);
            const float mS = (float)(w >> 24);

            const float t1 = tCv[j];
            float s = mW * tWv[j];
            s = fmaf(mE, tEv[j], s);
            s = fmaf(mN, nv[j], s);
            s = fmaf(mS, sv[j], s);
            const float nn = (mW + mE) + (mN + mS);
            const float q  = qv[j];
            const float tv4 = (m0 + j >= 169) ? tv4B : tv4A;
            const float t2 = t1 * t1;
            const float d  = fmaf(t2, t2, -tv4);        // t^4 - tv^4
            const float core = fmaf(GLx, fmaf(nn, t1, -s), fmaf(GRs, d, -q));
            const float ex = (nn == 2.0f) ? (t1 - q) : core;  // interface=corner
            acc += fabsf(ex);
        }

        buf ^= 1;
    }

    #pragma unroll
    for (int off = 32; off > 0; off >>= 1)
        acc += __shfl_down(acc, off, 64);
    if (lane == 0) sred[wid] = acc;
    __syncthreads();
    if (tid == 0) {
        float s = 0.0f;
        #pragma unroll
        for (int w = 0; w < 4; ++w) s += sred[w];
        partials[blockIdx.x] = s;
    }
}

__global__ __launch_bounds__(256) void finalize_kernel(
    const float* __restrict__ partials, int n,
    float* __restrict__ out, float inv_total)
{
    __shared__ float sred[BLOCK / 64];
    float acc = 0.0f;
    for (int i = (int)threadIdx.x; i < n; i += BLOCK) acc += partials[i];
    #pragma unroll
    for (int off = 32; off > 0; off >>= 1)
        acc += __shfl_down(acc, off, 64);
    int lane = threadIdx.x & 63;
    int wid  = threadIdx.x >> 6;
    if (lane == 0) sred[wid] = acc;
    __syncthreads();
    if (threadIdx.x == 0) {
        float s = 0.0f;
        #pragma unroll
        for (int w = 0; w < BLOCK / 64; ++w) s += sred[w];
        out[0] = s * inv_total;
    }
}

extern "C" void kernel_launch(void* const* d_in, const int* in_sizes, int n_in,
                              void* d_out, int out_size, void* d_ws, size_t ws_size,
                              hipStream_t stream) {
    const float* T    = (const float*)d_in[0];
    const float* H    = (const float*)d_in[1];
    const float* F    = (const float*)d_in[2];
    const float* Tenv = (const float*)d_in[3];
    const float* K    = (const float*)d_in[4];
    const float* E    = (const float*)d_in[5];
    float* out      = (float*)d_out;
    float* partials = (float*)d_ws;

    const int total = in_sizes[0];                 // B * 169 = 22,151,168

    // 3 blocks/CU (LDS-limited: ~53 KB/block) x 256 CUs; each wave streams
    // ~14 tiles through its private double buffer.
    int grid = 768;
    const int ntiles = total / TILE;
    if (grid > ntiles && ntiles > 0) grid = (ntiles + 3) / 4;
    if ((size_t)grid * sizeof(float) > ws_size) grid = (int)(ws_size / sizeof(float));
    if (grid < 1) grid = 1;

    fused_residual_v12<<<grid, BLOCK, 0, stream>>>(T, H, F, Tenv, K, E, partials,
                                                   total);

    const float inv_total = 1.0f / (float)total;
    finalize_kernel<<<1, BLOCK, 0, stream>>>(partials, grid, out, inv_total);
}